// Round 15
// baseline (784.156 us; speedup 1.0000x reference)
//
#include <hip/hip_runtime.h>

#define EDIM 1024
#define LNUM 24
#define FDIM 4096
#define NB 256   // persistent blocks, 1 per CU
#define NT 512   // 8 waves per block

__device__ __forceinline__ float wave_sum(float v) {
#pragma unroll
    for (int off = 32; off > 0; off >>= 1) v += __shfl_xor(v, off, 64);
    return v;
}

// Coherent (MALL-visible) accessors for cross-block data. No fences anywhere.
__device__ __forceinline__ float2 cload2(const float* p) {
    double d = __hip_atomic_load((const double*)p, __ATOMIC_RELAXED,
                                 __HIP_MEMORY_SCOPE_AGENT);
    float2 r;
    __builtin_memcpy(&r, &d, 8);
    return r;
}
__device__ __forceinline__ void cstore1(float* p, float v) {
    __hip_atomic_store(p, v, __ATOMIC_RELAXED, __HIP_MEMORY_SCOPE_AGENT);
}
__device__ __forceinline__ void cstore2(float* p, float2 v) {
    double d;
    __builtin_memcpy(&d, &v, 8);
    __hip_atomic_store((double*)p, d, __ATOMIC_RELAXED, __HIP_MEMORY_SCOPE_AGENT);
}

// Pin ordering: stores above, prefetch loads below (needed for counted vmcnt).
#define FENCE()                            \
    do {                                   \
        asm volatile("" ::: "memory");     \
        __builtin_amdgcn_sched_barrier(0); \
    } while (0)

// Intra-block barrier that does NOT drain vmcnt.
__device__ __forceinline__ void lbar() {
    asm volatile("s_waitcnt lgkmcnt(0)" ::: "memory");
    __builtin_amdgcn_sched_barrier(0);
    __builtin_amdgcn_s_barrier();
    asm volatile("" ::: "memory");
    __builtin_amdgcn_sched_barrier(0);
}

// Device-wide DIGEST barrier, counted vmcnt.
//  - arrival: ONE PLAIN sc1 STORE per block to its own word done[b]=epoch.
//    No atomic RMW anywhere -> no arrival serialization (round 8/9/14 cost),
//    and polled lines carry no RMW traffic (round-13 failure mode absent).
//  - detect: every block self-detects: wave 0's 64 lanes read 4 words each
//    (256 total, 16 lines), __all() ballot, sleep backoff. No release hop.
//  - epoch monotonic 1..96; done[] memset to 0 once per launch.
template <int P>
__device__ __forceinline__ void dbar(unsigned* done, unsigned& ep) {
    ++ep;
    asm volatile("s_waitcnt vmcnt(%0) lgkmcnt(0)" ::"i"(P) : "memory");
    __builtin_amdgcn_sched_barrier(0);
    __builtin_amdgcn_s_barrier();  // all waves of this block: stores drained
    if (threadIdx.x == 0)
        __hip_atomic_store(&done[blockIdx.x], ep, __ATOMIC_RELAXED,
                           __HIP_MEMORY_SCOPE_AGENT);
    if (threadIdx.x < 64) {  // wave 0 detects completion of all 256 blocks
        const unsigned long long* dp =
            (const unsigned long long*)(done + 4 * threadIdx.x);
        int guard = 0;
        for (;;) {
            const unsigned long long d0 = __hip_atomic_load(
                dp, __ATOMIC_RELAXED, __HIP_MEMORY_SCOPE_AGENT);
            const unsigned long long d1 = __hip_atomic_load(
                dp + 1, __ATOMIC_RELAXED, __HIP_MEMORY_SCOPE_AGENT);
            const bool ok = (unsigned)d0 >= ep && (unsigned)(d0 >> 32) >= ep &&
                            (unsigned)d1 >= ep && (unsigned)(d1 >> 32) >= ep;
            if (__all(ok)) break;
            __builtin_amdgcn_s_sleep(2);
            if (++guard > (1 << 22)) break;  // fail-fast bailout
        }
    }
    __builtin_amdgcn_s_barrier();
    asm volatile("" ::: "memory");
    __builtin_amdgcn_sched_barrier(0);
}

__device__ __forceinline__ float dot16(const float4& p0, const float4& p1,
                                       const float4& p2, const float4& p3,
                                       const float4& a, const float4& b,
                                       const float4& c, const float4& d) {
    return p0.x * a.x + p0.y * a.y + p0.z * a.z + p0.w * a.w +
           p1.x * b.x + p1.y * b.y + p1.z * b.z + p1.w * b.w +
           p2.x * c.x + p2.y * c.y + p2.z * c.z + p2.w * c.w +
           p3.x * d.x + p3.y * d.y + p3.z * d.z + p3.w * d.w;
}

__device__ __forceinline__ float dot1024_pref(const float4& p0, const float4& p1,
                                              const float4& p2, const float4& p3,
                                              const float* op, int lane) {
    const float4* o = (const float4*)op;
    return wave_sum(dot16(p0, p1, p2, p3, o[lane], o[lane + 64], o[lane + 128],
                          o[lane + 192]));
}

__device__ __forceinline__ float dot512_pref(const float4& p0, const float4& p1,
                                             const float* op, int lane) {
    const float4* o = (const float4*)op;
    const float4 a = o[lane], b4 = o[lane + 64];
    return wave_sum(p0.x * a.x + p0.y * a.y + p0.z * a.z + p0.w * a.w +
                    p1.x * b4.x + p1.y * b4.y + p1.z * b4.z + p1.w * b4.w);
}

__global__ __launch_bounds__(NT, 2) void rwkv_persistent(
    const float* __restrict__ x_in, const float* __restrict__ state,
    const float* __restrict__ ln1w, const float* __restrict__ ln1b,
    const float* __restrict__ ln2w, const float* __restrict__ ln2b,
    const float* __restrict__ td, const float* __restrict__ tf,
    const float* __restrict__ key, const float* __restrict__ ow,
    const float* __restrict__ mixk, const float* __restrict__ mixv,
    const float* __restrict__ mixr, const float* __restrict__ mixkf,
    const float* __restrict__ mixrf, const float* __restrict__ kffn,
    const float* __restrict__ rffn, const float* __restrict__ vffn,
    float* __restrict__ out, float* __restrict__ ws, unsigned* __restrict__ done) {
    __shared__ float smem[FDIM + 32];
    float* red = smem + FDIM;  // [0..15] dot partials; [16..23] half partials

    // Coherent cross-block buffers (partials-forward scheme):
    float* xmat = ws;            // [1024] x_l   (A writes own 4-slice)
    float* sxbuf = ws + 1024;    // [1024] sx_l  (C writes own 4-slice)
    float* kbuf = ws + 2048;     // [1024]
    float* vbuf = ws + 3072;     // [1024]
    float* rkh = ws + 4096;      // [2][1024] k-mat r-row half dots
    float* sxh = ws + 6144;      // [2][1024] ow-row half dots
    float* kfbuf = ws + 8192;    // [4096]
    float* rdh = ws + 12288;     // [2][1024] rfw-row half dots
    float* xpart = ws + 14336;   // [4][1024] vfw-row quarter dots

    float* sa_out = out + EDIM;
    float* sb_out = sa_out + LNUM * EDIM;
    float* sc_out = sb_out + LNUM * EDIM;
    float* sd_out = sc_out + LNUM * EDIM;

    const int t = threadIdx.x;
    const int b = blockIdx.x;
    const int w = t >> 6;
    const int lane = t & 63;
    const int gw = (b << 3) + w;           // 0..2047
    const int rrow = (b << 2) + (w >> 1);  // r-mat / ow / rfw row, halves
    const int rh = w & 1;
    const int drow = (b << 2) + (w >> 2);  // vfw rows, quarters
    const int dch = w & 3;
    const bool slicer = ((t >> 1) == b);   // threads 2b, 2b+1 own elems [4b,4b+4)
    unsigned ep = 0;

    // Prefetch registers (named, never runtime-indexed — rule #20)
    float4 pA0, pA1, pA2, pA3, rA0, rA1;
    float4 pB0, pB1;
    float4 pC10, pC11, pC12, pC13, pC20, pC21, pC22, pC23, rC0, rC1;
    float4 pD0, pD1, pD2, pD3, pD4, pD5, pD6, pD7;

    // Prologue: layer-0 phase-A weights (k/v full row gw; r half-row).
    {
        const float4* qA = (const float4*)(key + ((size_t)gw << 10));
        pA0 = qA[lane]; pA1 = qA[lane + 64]; pA2 = qA[lane + 128]; pA3 = qA[lane + 192];
        const float4* qR =
            (const float4*)(key + ((size_t)(2048 + rrow) << 10) + (rh << 9));
        rA0 = qR[lane]; rA1 = qR[lane + 64];
    }

    for (int l = 0; l < LNUM; ++l) {
        const float* owl = ow + (size_t)l * EDIM * EDIM;
        const float* kfl = kffn + (size_t)l * FDIM * EDIM;
        const float* rfl = rffn + (size_t)l * EDIM * EDIM;
        const float* vfl = vffn + (size_t)l * EDIM * FDIM;
        const int le = l * EDIM;
        const int bsel = (l << 2) & 255;

        // ========== Phase A: assemble x, LN1, k/v/r matvec partials ==========
        {
            float2 xv;
            if (l == 0) {
                xv = ((const float2*)x_in)[t];
            } else {
                // assemble x = sx + (Σ vfw-quarters) * sigmoid-gate  (prev layer D/C)
                const float2 sx2 = cload2(sxbuf + 2 * t);
                const float2 xp0 = cload2(xpart + 2 * t);
                const float2 xp1 = cload2(xpart + 1024 + 2 * t);
                const float2 xp2 = cload2(xpart + 2048 + 2 * t);
                const float2 xp3 = cload2(xpart + 3072 + 2 * t);
                const float2 rd0 = cload2(rdh + 2 * t);
                const float2 rd1 = cload2(rdh + 1024 + 2 * t);
                const float gx = 1.0f / (1.0f + expf(rd0.x + rd1.x));
                const float gy = 1.0f / (1.0f + expf(rd0.y + rd1.y));
                xv.x = sx2.x + (xp0.x + xp1.x + xp2.x + xp3.x) * gx;
                xv.y = sx2.y + (xp0.y + xp1.y + xp2.y + xp3.y) * gy;
                if (slicer) cstore2(xmat + 2 * t, xv);  // materialize own slice for C
            }
            float s = xv.x + xv.y, s2 = xv.x * xv.x + xv.y * xv.y;
#pragma unroll
            for (int off = 32; off > 0; off >>= 1) {
                s += __shfl_xor(s, off, 64);
                s2 += __shfl_xor(s2, off, 64);
            }
            if (lane == 0) { red[w] = s; red[8 + w] = s2; }
            lbar();
            float ts = 0.0f, ts2 = 0.0f;
#pragma unroll
            for (int i = 0; i < 8; ++i) { ts += red[i]; ts2 += red[8 + i]; }
            const float mu = ts * (1.0f / 1024.0f);
            const float inv = rsqrtf(ts2 * (1.0f / 1024.0f) - mu * mu + 1e-5f);
            const float2 wv = ((const float2*)(ln1w + le))[t];
            const float2 bv = ((const float2*)(ln1b + le))[t];
            const float2 xn = make_float2((xv.x - mu) * inv * wv.x + bv.x,
                                          (xv.y - mu) * inv * wv.y + bv.y);
            if (b == bsel) ((float2*)(sa_out + le))[t] = xn;  // sa
            const float2 sav = ((const float2*)(state + le))[t];
            const float2 mk = ((const float2*)(mixk + le))[t];
            const float2 mv = ((const float2*)(mixv + le))[t];
            const float2 mr = ((const float2*)(mixr + le))[t];
            ((float2*)smem)[t] = make_float2(xn.x + mk.x * sav.x, xn.y + mk.y * sav.y);
            ((float2*)(smem + 1024))[t] =
                make_float2(xn.x + mv.x * sav.x, xn.y + mv.y * sav.y);
            ((float2*)(smem + 2048))[t] =
                make_float2(xn.x + mr.x * sav.x, xn.y + mr.y * sav.y);
            lbar();
            const int mat = gw >> 10;  // 0 -> k row, 1 -> v row (prefetched)
            const float d1 = dot1024_pref(pA0, pA1, pA2, pA3, smem + (mat << 10), lane);
            if (lane == 0) {
                if (mat == 0) cstore1(kbuf + gw, expf(d1));
                else          cstore1(vbuf + gw - 1024, d1);
            }
            const float d2 = dot512_pref(rA0, rA1, smem + 2048 + (rh << 9), lane);
            if (lane == 0) cstore1(rkh + (rh << 10) + rrow, d2);  // half partial
        }
        FENCE();
        {   // window A->B: issue pB (ow half-row) + pC1 (kfw row gw)
            const float4* qB = (const float4*)(owl + ((size_t)rrow << 10) + (rh << 9));
            pB0 = qB[lane]; pB1 = qB[lane + 64];
            const float4* q1 = (const float4*)(kfl + ((size_t)gw << 10));
            pC10 = q1[lane]; pC11 = q1[lane + 64]; pC12 = q1[lane + 128]; pC13 = q1[lane + 192];
        }
        dbar<6>(done, ep);

        // ========== Phase B: WKV + ow matvec half-partials ==========
        {
            const float2 k2 = cload2(kbuf + 2 * t);
            const float2 v2 = cload2(vbuf + 2 * t);
            const float2 r0 = cload2(rkh + 2 * t);
            const float2 r1 = cload2(rkh + 1024 + 2 * t);
            const float2 r2 = make_float2(expf(r0.x + r1.x) + 1.0f,
                                          expf(r0.y + r1.y) + 1.0f);
            const float2 tf2 = ((const float2*)(tf + le))[t];
            const float2 sb2 = ((const float2*)(state + 1 * LNUM * EDIM + le))[t];
            const float2 sc2 = ((const float2*)(state + 2 * LNUM * EDIM + le))[t];
            const float g0 =
                (sb2.x + tf2.x * k2.x * v2.x) / (sc2.x * r2.x + tf2.x * k2.x * r2.x);
            const float g1 =
                (sb2.y + tf2.y * k2.y * v2.y) / (sc2.y * r2.y + tf2.y * k2.y * r2.y);
            ((float2*)smem)[t] = make_float2(g0, g1);
            if (b == bsel + 1) {
                const float2 td2 = ((const float2*)(td + le))[t];
                ((float2*)(sb_out + le))[t] =
                    make_float2(sb2.x * td2.x + k2.x * v2.x, sb2.y * td2.y + k2.y * v2.y);
                ((float2*)(sc_out + le))[t] =
                    make_float2(sc2.x * td2.x + k2.x, sc2.y * td2.y + k2.y);
            }
            lbar();
            const float pd = dot512_pref(pB0, pB1, smem + (rh << 9), lane);
            if (lane == 0) cstore1(sxh + (rh << 10) + rrow, pd);  // half partial
        }
        FENCE();
        {   // window B->C: issue pC2 (kfw row gw+2048) + rC (rfw half-row)
            const float4* q2 = (const float4*)(kfl + ((size_t)(gw + 2048) << 10));
            pC20 = q2[lane]; pC21 = q2[lane + 64]; pC22 = q2[lane + 128]; pC23 = q2[lane + 192];
            const float4* qR = (const float4*)(rfl + ((size_t)rrow << 10) + (rh << 9));
            rC0 = qR[lane]; rC1 = qR[lane + 64];
        }
        dbar<6>(done, ep);

        // ========== Phase C: assemble sx, LN2, kfw/rfw matvec partials ==========
        {
            float2 xl;
            if (l == 0) xl = ((const float2*)x_in)[t];
            else        xl = cload2(xmat + 2 * t);
            const float2 h0 = cload2(sxh + 2 * t);
            const float2 h1 = cload2(sxh + 1024 + 2 * t);
            const float2 sxv = make_float2(xl.x + h0.x + h1.x, xl.y + h0.y + h1.y);
            if (slicer) cstore2(sxbuf + 2 * t, sxv);  // materialize own slice
            float s = sxv.x + sxv.y, s2 = sxv.x * sxv.x + sxv.y * sxv.y;
#pragma unroll
            for (int off = 32; off > 0; off >>= 1) {
                s += __shfl_xor(s, off, 64);
                s2 += __shfl_xor(s2, off, 64);
            }
            if (lane == 0) { red[w] = s; red[8 + w] = s2; }
            lbar();
            float ts = 0.0f, ts2 = 0.0f;
#pragma unroll
            for (int i = 0; i < 8; ++i) { ts += red[i]; ts2 += red[8 + i]; }
            const float mu = ts * (1.0f / 1024.0f);
            const float inv = rsqrtf(ts2 * (1.0f / 1024.0f) - mu * mu + 1e-5f);
            const float2 wv = ((const float2*)(ln2w + le))[t];
            const float2 bv = ((const float2*)(ln2b + le))[t];
            const float2 x2 = make_float2((sxv.x - mu) * inv * wv.x + bv.x,
                                          (sxv.y - mu) * inv * wv.y + bv.y);
            if (b == bsel + 2) ((float2*)(sd_out + le))[t] = x2;  // sd
            const float2 sdv = ((const float2*)(state + 3 * LNUM * EDIM + le))[t];
            const float2 mkf = ((const float2*)(mixkf + le))[t];
            const float2 mrf = ((const float2*)(mixrf + le))[t];
            ((float2*)smem)[t] = make_float2(x2.x + mkf.x * sdv.x, x2.y + mkf.y * sdv.y);
            ((float2*)(smem + 1024))[t] =
                make_float2(x2.x + mrf.x * sdv.x, x2.y + mrf.y * sdv.y);
            lbar();
            const float d1 = dot1024_pref(pC10, pC11, pC12, pC13, smem, lane);
            if (lane == 0) { const float rl = fmaxf(d1, 0.0f); cstore1(kfbuf + gw, rl * rl); }
            const float d2 = dot1024_pref(pC20, pC21, pC22, pC23, smem, lane);
            if (lane == 0) { const float rl = fmaxf(d2, 0.0f); cstore1(kfbuf + gw + 2048, rl * rl); }
            const float d3 = dot512_pref(rC0, rC1, smem + 1024 + (rh << 9), lane);
            if (lane == 0) cstore1(rdh + (rh << 10) + rrow, d3);  // half partial
        }
        FENCE();
        {   // window C->D: issue both vfw chunk-units
            const float4* q1 = (const float4*)(vfl + ((size_t)drow << 12) + (dch << 10));
            pD0 = q1[lane]; pD1 = q1[lane + 64]; pD2 = q1[lane + 128]; pD3 = q1[lane + 192];
            const float4* q2 =
                (const float4*)(vfl + ((size_t)(drow + 2) << 12) + (dch << 10));
            pD4 = q2[lane]; pD5 = q2[lane + 64]; pD6 = q2[lane + 128]; pD7 = q2[lane + 192];
        }
        dbar<8>(done, ep);

        // ========== Phase D: vfw matvec quarter-partials ==========
        {
            const double* kfd = (const double*)kfbuf;
#pragma unroll
            for (int j = 0; j < 4; ++j)
                ((double*)smem)[t + j * 512] = __hip_atomic_load(
                    kfd + t + j * 512, __ATOMIC_RELAXED, __HIP_MEMORY_SCOPE_AGENT);
            lbar();
            const float pd0 = dot1024_pref(pD0, pD1, pD2, pD3, smem + (dch << 10), lane);
            const float pd1 = dot1024_pref(pD4, pD5, pD6, pD7, smem + (dch << 10), lane);
            if (lane == 0) {
                cstore1(xpart + (dch << 10) + drow, pd0);
                cstore1(xpart + (dch << 10) + drow + 2, pd1);
            }
        }
        if (l < LNUM - 1) {
            FENCE();
            {   // window D->A': next layer's phase-A weights
                const float* keyn = key + (size_t)(l + 1) * 3 * EDIM * EDIM;
                const float4* qA = (const float4*)(keyn + ((size_t)gw << 10));
                pA0 = qA[lane]; pA1 = qA[lane + 64]; pA2 = qA[lane + 128]; pA3 = qA[lane + 192];
                const float4* qR =
                    (const float4*)(keyn + ((size_t)(2048 + rrow) << 10) + (rh << 9));
                rA0 = qR[lane]; rA1 = qR[lane + 64];
            }
            dbar<6>(done, ep);
        }
    }

    // ========== Epilogue: assemble final x' and write out[0:1024] ==========
    FENCE();
    dbar<0>(done, ep);
    if (slicer) {
        const float2 sx2 = cload2(sxbuf + 2 * t);
        const float2 xp0 = cload2(xpart + 2 * t);
        const float2 xp1 = cload2(xpart + 1024 + 2 * t);
        const float2 xp2 = cload2(xpart + 2048 + 2 * t);
        const float2 xp3 = cload2(xpart + 3072 + 2 * t);
        const float2 rd0 = cload2(rdh + 2 * t);
        const float2 rd1 = cload2(rdh + 1024 + 2 * t);
        const float gx = 1.0f / (1.0f + expf(rd0.x + rd1.x));
        const float gy = 1.0f / (1.0f + expf(rd0.y + rd1.y));
        out[2 * t] = sx2.x + (xp0.x + xp1.x + xp2.x + xp3.x) * gx;
        out[2 * t + 1] = sx2.y + (xp0.y + xp1.y + xp2.y + xp3.y) * gy;
    }
}

extern "C" void kernel_launch(void* const* d_in, const int* in_sizes, int n_in,
                              void* d_out, int out_size, void* d_ws, size_t ws_size,
                              hipStream_t stream) {
    const float* x_in = (const float*)d_in[0];
    const float* state = (const float*)d_in[1];
    const float* ln1w = (const float*)d_in[2];
    const float* ln1b = (const float*)d_in[3];
    const float* ln2w = (const float*)d_in[4];
    const float* ln2b = (const float*)d_in[5];
    const float* td = (const float*)d_in[6];
    const float* tf = (const float*)d_in[7];
    const float* key = (const float*)d_in[8];
    const float* ow = (const float*)d_in[9];
    const float* mixk = (const float*)d_in[10];
    const float* mixv = (const float*)d_in[11];
    const float* mixr = (const float*)d_in[12];
    const float* mixkf = (const float*)d_in[13];
    const float* mixrf = (const float*)d_in[14];
    const float* kffn = (const float*)d_in[15];
    const float* rffn = (const float*)d_in[16];
    const float* vffn = (const float*)d_in[17];

    float* out = (float*)d_out;
    float* ws = (float*)d_ws;

    // Vector region: 18432 floats = 72 KB. Digest-barrier state at 96 KB:
    // 256 contiguous done-words (1 KB, 16 lines), plain-store arrivals.
    unsigned* done = (unsigned*)((char*)d_ws + 96 * 1024);

    hipMemsetAsync(done, 0, 1024, stream);  // deterministic per replay
    rwkv_persistent<<<NB, NT, 0, stream>>>(x_in, state, ln1w, ln1b, ln2w, ln2b, td, tf,
                                           key, ow, mixk, mixv, mixr, mixkf, mixrf,
                                           kffn, rffn, vffn, out, ws, done);
}

// Round 16
// 501.300 us; speedup vs baseline: 1.5642x; 1.5642x over previous
//
#include <hip/hip_runtime.h>

#define EDIM 1024
#define LNUM 24
#define FDIM 4096
#define NB 256   // persistent blocks, 1 per CU
#define NT 512   // 8 waves per block

__device__ __forceinline__ float wave_sum(float v) {
#pragma unroll
    for (int off = 32; off > 0; off >>= 1) v += __shfl_xor(v, off, 64);
    return v;
}

// Coherent (MALL-visible) accessors for cross-block data.
__device__ __forceinline__ float2 cload2(const float* p) {
    double d = __hip_atomic_load((const double*)p, __ATOMIC_RELAXED,
                                 __HIP_MEMORY_SCOPE_AGENT);
    float2 r;
    __builtin_memcpy(&r, &d, 8);
    return r;
}
__device__ __forceinline__ void cstore1(float* p, float v) {
    __hip_atomic_store(p, v, __ATOMIC_RELAXED, __HIP_MEMORY_SCOPE_AGENT);
}

#define FENCE()                            \
    do {                                   \
        asm volatile("" ::: "memory");     \
        __builtin_amdgcn_sched_barrier(0); \
    } while (0)

// Intra-block barrier that does NOT drain vmcnt.
__device__ __forceinline__ void lbar() {
    asm volatile("s_waitcnt lgkmcnt(0)" ::: "memory");
    __builtin_amdgcn_sched_barrier(0);
    __builtin_amdgcn_s_barrier();
    asm volatile("" ::: "memory");
    __builtin_amdgcn_sched_barrier(0);
}

// Device-wide barrier (round-10 topology: best measured, 520 us base).
// Wave-conditional drain: only wave 0 carries coherent stores, so only wave 0
// executes vmcnt(P); waves 1-7 skip the VMEM drain entirely (their window
// loads stream across the barrier untouched).
template <int P>
__device__ __forceinline__ void gbar(unsigned* grp, unsigned* flags, unsigned& bi,
                                     int w) {
    if (w == 0) {
        asm volatile("s_waitcnt vmcnt(%0) lgkmcnt(0)" ::"i"(P) : "memory");
    } else {
        asm volatile("s_waitcnt lgkmcnt(0)" ::: "memory");
    }
    __builtin_amdgcn_sched_barrier(0);
    __builtin_amdgcn_s_barrier();
    const unsigned bi1 = bi + 1u;
    if (threadIdx.x == 0) {
        const int g = blockIdx.x & 7;
        unsigned o = __hip_atomic_fetch_add(&grp[g << 4], 1u, __ATOMIC_RELAXED,
                                            __HIP_MEMORY_SCOPE_AGENT);
        if ((o & 31u) == 31u) {  // group-last for this epoch
            const unsigned tgt = 32u * bi1;
            int guard = 0;
            for (;;) {
                unsigned mn = 0xffffffffu;
#pragma unroll
                for (int i = 0; i < 8; ++i) {
                    unsigned v = __hip_atomic_load(&grp[i << 4], __ATOMIC_RELAXED,
                                                   __HIP_MEMORY_SCOPE_AGENT);
                    mn = (v < mn) ? v : mn;
                }
                if (mn >= tgt) break;
                __builtin_amdgcn_s_sleep(1);
                if (++guard > (1 << 20)) break;  // fail-fast bailout
            }
            // release this group's 32 blocks (one private flag line each)
#pragma unroll 8
            for (int j = 0; j < 32; ++j)
                __hip_atomic_store(&flags[(g + 8 * j) << 4], bi1, __ATOMIC_RELAXED,
                                   __HIP_MEMORY_SCOPE_AGENT);
        } else {
            int guard = 0;
            while (__hip_atomic_load(&flags[blockIdx.x << 4], __ATOMIC_RELAXED,
                                     __HIP_MEMORY_SCOPE_AGENT) < bi1) {
                __builtin_amdgcn_s_sleep(1);
                if (++guard > (1 << 20)) break;
            }
        }
    }
    __builtin_amdgcn_s_barrier();
    asm volatile("" ::: "memory");
    __builtin_amdgcn_sched_barrier(0);
    ++bi;
}

__device__ __forceinline__ float dot16(const float4& p0, const float4& p1,
                                       const float4& p2, const float4& p3,
                                       const float4& a, const float4& b,
                                       const float4& c, const float4& d) {
    return p0.x * a.x + p0.y * a.y + p0.z * a.z + p0.w * a.w +
           p1.x * b.x + p1.y * b.y + p1.z * b.z + p1.w * b.w +
           p2.x * c.x + p2.y * c.y + p2.z * c.z + p2.w * c.w +
           p3.x * d.x + p3.y * d.y + p3.z * d.z + p3.w * d.w;
}

__device__ __forceinline__ float dot1024_pref(const float4& p0, const float4& p1,
                                              const float4& p2, const float4& p3,
                                              const float* op, int lane) {
    const float4* o = (const float4*)op;
    return wave_sum(dot16(p0, p1, p2, p3, o[lane], o[lane + 64], o[lane + 128],
                          o[lane + 192]));
}

__device__ __forceinline__ float dot512_pref(const float4& p0, const float4& p1,
                                             const float* op, int lane) {
    const float4* o = (const float4*)op;
    const float4 a = o[lane], b4 = o[lane + 64];
    return wave_sum(p0.x * a.x + p0.y * a.y + p0.z * a.z + p0.w * a.w +
                    p1.x * b4.x + p1.y * b4.y + p1.z * b4.z + p1.w * b4.w);
}

__global__ __launch_bounds__(NT, 2) void rwkv_persistent(
    const float* __restrict__ x_in, const float* __restrict__ state,
    const float* __restrict__ ln1w, const float* __restrict__ ln1b,
    const float* __restrict__ ln2w, const float* __restrict__ ln2b,
    const float* __restrict__ td, const float* __restrict__ tf,
    const float* __restrict__ key, const float* __restrict__ ow,
    const float* __restrict__ mixk, const float* __restrict__ mixv,
    const float* __restrict__ mixr, const float* __restrict__ mixkf,
    const float* __restrict__ mixrf, const float* __restrict__ kffn,
    const float* __restrict__ rffn, const float* __restrict__ vffn,
    float* __restrict__ out, float* __restrict__ ws, unsigned* __restrict__ grp,
    unsigned* __restrict__ flags) {
    __shared__ float smem[FDIM + 64];
    float* red = smem + FDIM;
    // red layout: [0..7] dot1 / stats-s; [8..15] dot2 / stats-s2;
    // [16..23] half-dots; [24..27] x slice (A->B); [28..31] sx slice (B->D);
    // [32..35] gates (C->D)

    // Coherent cross-block buffers — FULL VALUES only (no partials):
    float* xnext = ws;          // [1024] next-layer x  (D tail, wave 0)
    float* sxbuf = ws + 1024;   // [1024] sx            (B tail, wave 0)
    float* kbuf = ws + 2048;    // [1024] exp(k)        (A tail, wave 0)
    float* vbuf = ws + 3072;    // [1024] v
    float* rbuf = ws + 4096;    // [1024] exp(r)+1
    float* kfbuf = ws + 5120;   // [4096] relu^2(kf)    (C tail, wave 0)

    float* sa_out = out + EDIM;
    float* sb_out = sa_out + LNUM * EDIM;
    float* sc_out = sb_out + LNUM * EDIM;
    float* sd_out = sc_out + LNUM * EDIM;

    const int t = threadIdx.x;
    const int b = blockIdx.x;
    const int w = t >> 6;
    const int lane = t & 63;
    const int gw = (b << 3) + w;           // 0..2047
    const int mat = b >> 7;                // 0 -> k rows, 1 -> v rows (uniform)
    const int rrow = (b << 2) + (w >> 1);  // r / ow / rfw row, halves
    const int rh = w & 1;
    const int drow = (b << 2) + (w >> 2);  // vfw rows, quarters
    const int dch = w & 3;
    const bool slicer = ((t >> 1) == b);   // threads 2b,2b+1 hold x[4b..4b+4)
    unsigned bi = 0;

    // Prefetch registers (named, never runtime-indexed — rule #20)
    float4 pA0, pA1, pA2, pA3, rA0, rA1;
    float4 pB0, pB1;
    float4 pC10, pC11, pC12, pC13, pC20, pC21, pC22, pC23, rC0, rC1;
    float4 pD0, pD1, pD2, pD3, pD4, pD5, pD6, pD7;

    // Prologue: layer-0 phase-A weights.
    {
        const float4* qA = (const float4*)(key + ((size_t)gw << 10));
        pA0 = qA[lane]; pA1 = qA[lane + 64]; pA2 = qA[lane + 128]; pA3 = qA[lane + 192];
        const float4* qR =
            (const float4*)(key + ((size_t)(2048 + rrow) << 10) + (rh << 9));
        rA0 = qR[lane]; rA1 = qR[lane + 64];
    }

    for (int l = 0; l < LNUM; ++l) {
        const float* owl = ow + (size_t)l * EDIM * EDIM;
        const float* kfl = kffn + (size_t)l * FDIM * EDIM;
        const float* rfl = rffn + (size_t)l * EDIM * EDIM;
        const float* vfl = vffn + (size_t)l * EDIM * FDIM;
        const int le = l * EDIM;
        const int bsel = (l << 2) & 255;

        // ========== Phase A: LN1 + k/v/r matvecs ==========
        {
            const float2 xv = (l == 0) ? ((const float2*)x_in)[t]
                                       : cload2(xnext + 2 * t);
            if (slicer) {  // stash own x slice for B's sx combine
                red[24 + ((t & 1) << 1)] = xv.x;
                red[25 + ((t & 1) << 1)] = xv.y;
            }
            float s = xv.x + xv.y, s2 = xv.x * xv.x + xv.y * xv.y;
#pragma unroll
            for (int off = 32; off > 0; off >>= 1) {
                s += __shfl_xor(s, off, 64);
                s2 += __shfl_xor(s2, off, 64);
            }
            if (lane == 0) { red[w] = s; red[8 + w] = s2; }
            lbar();
            float ts = 0.0f, ts2 = 0.0f;
#pragma unroll
            for (int i = 0; i < 8; ++i) { ts += red[i]; ts2 += red[8 + i]; }
            const float mu = ts * (1.0f / 1024.0f);
            const float inv = rsqrtf(ts2 * (1.0f / 1024.0f) - mu * mu + 1e-5f);
            const float2 wv = ((const float2*)(ln1w + le))[t];
            const float2 bv = ((const float2*)(ln1b + le))[t];
            const float2 xn = make_float2((xv.x - mu) * inv * wv.x + bv.x,
                                          (xv.y - mu) * inv * wv.y + bv.y);
            if (b == bsel) ((float2*)(sa_out + le))[t] = xn;  // sa (host-only)
            const float2 sav = ((const float2*)(state + le))[t];
            const float2 mk = ((const float2*)(mixk + le))[t];
            const float2 mv = ((const float2*)(mixv + le))[t];
            const float2 mr = ((const float2*)(mixr + le))[t];
            ((float2*)smem)[t] = make_float2(xn.x + mk.x * sav.x, xn.y + mk.y * sav.y);
            ((float2*)(smem + 1024))[t] =
                make_float2(xn.x + mv.x * sav.x, xn.y + mv.y * sav.y);
            ((float2*)(smem + 2048))[t] =
                make_float2(xn.x + mr.x * sav.x, xn.y + mr.y * sav.y);
            lbar();
            const float d1 = dot1024_pref(pA0, pA1, pA2, pA3, smem + (mat << 10), lane);
            const float d2 = dot512_pref(rA0, rA1, smem + 2048 + (rh << 9), lane);
            if (lane == 0) { red[w] = d1; red[16 + w] = d2; }
            lbar();
            if (w == 0) {  // wave-0 tail: combine + coalesced coherent stores
                if (lane < 8) {
                    const float dv = red[lane];
                    if (mat == 0) cstore1(kbuf + (b << 3) + lane, expf(dv));
                    else          cstore1(vbuf + ((b - 128) << 3) + lane, dv);
                } else if (lane < 12) {
                    const int j = lane - 8;
                    cstore1(rbuf + (b << 2) + j,
                            expf(red[16 + 2 * j] + red[17 + 2 * j]) + 1.0f);
                }
            }
        }
        FENCE();
        {   // window A->B: pB (ow half-row) + pC1 (kfw row gw) = 6 loads
            const float4* qB = (const float4*)(owl + ((size_t)rrow << 10) + (rh << 9));
            pB0 = qB[lane]; pB1 = qB[lane + 64];
            const float4* q1 = (const float4*)(kfl + ((size_t)gw << 10));
            pC10 = q1[lane]; pC11 = q1[lane + 64]; pC12 = q1[lane + 128]; pC13 = q1[lane + 192];
        }
        gbar<6>(grp, flags, bi, w);

        // ========== Phase B: WKV + ow matvec ==========
        {
            const float2 k2 = cload2(kbuf + 2 * t);
            const float2 v2 = cload2(vbuf + 2 * t);
            const float2 r2 = cload2(rbuf + 2 * t);
            const float2 tf2 = ((const float2*)(tf + le))[t];
            const float2 sb2 = ((const float2*)(state + 1 * LNUM * EDIM + le))[t];
            const float2 sc2 = ((const float2*)(state + 2 * LNUM * EDIM + le))[t];
            const float g0 =
                (sb2.x + tf2.x * k2.x * v2.x) / (sc2.x * r2.x + tf2.x * k2.x * r2.x);
            const float g1 =
                (sb2.y + tf2.y * k2.y * v2.y) / (sc2.y * r2.y + tf2.y * k2.y * r2.y);
            ((float2*)smem)[t] = make_float2(g0, g1);
            if (b == bsel + 1) {  // sb'/sc' (host-only)
                const float2 td2 = ((const float2*)(td + le))[t];
                ((float2*)(sb_out + le))[t] =
                    make_float2(sb2.x * td2.x + k2.x * v2.x, sb2.y * td2.y + k2.y * v2.y);
                ((float2*)(sc_out + le))[t] =
                    make_float2(sc2.x * td2.x + k2.x, sc2.y * td2.y + k2.y);
            }
            lbar();
            const float pd = dot512_pref(pB0, pB1, smem + (rh << 9), lane);
            if (lane == 0) red[w] = pd;
            lbar();
            if (w == 0 && lane < 4) {  // wave-0 tail: sx = x + ow@g
                const float sx = red[24 + lane] + red[2 * lane] + red[2 * lane + 1];
                cstore1(sxbuf + (b << 2) + lane, sx);
                red[28 + lane] = sx;  // keep slice local for D
            }
        }
        FENCE();
        {   // window B->C: pC2 (kfw row gw+2048) + rC (rfw half-row) = 6 loads
            const float4* q2 = (const float4*)(kfl + ((size_t)(gw + 2048) << 10));
            pC20 = q2[lane]; pC21 = q2[lane + 64]; pC22 = q2[lane + 128]; pC23 = q2[lane + 192];
            const float4* qR = (const float4*)(rfl + ((size_t)rrow << 10) + (rh << 9));
            rC0 = qR[lane]; rC1 = qR[lane + 64];
        }
        gbar<6>(grp, flags, bi, w);

        // ========== Phase C: LN2 + kfw/rfw matvecs ==========
        {
            const float2 sxv = cload2(sxbuf + 2 * t);
            float s = sxv.x + sxv.y, s2 = sxv.x * sxv.x + sxv.y * sxv.y;
#pragma unroll
            for (int off = 32; off > 0; off >>= 1) {
                s += __shfl_xor(s, off, 64);
                s2 += __shfl_xor(s2, off, 64);
            }
            if (lane == 0) { red[w] = s; red[8 + w] = s2; }
            lbar();
            float ts = 0.0f, ts2 = 0.0f;
#pragma unroll
            for (int i = 0; i < 8; ++i) { ts += red[i]; ts2 += red[8 + i]; }
            const float mu = ts * (1.0f / 1024.0f);
            const float inv = rsqrtf(ts2 * (1.0f / 1024.0f) - mu * mu + 1e-5f);
            const float2 wv = ((const float2*)(ln2w + le))[t];
            const float2 bv = ((const float2*)(ln2b + le))[t];
            const float2 x2 = make_float2((sxv.x - mu) * inv * wv.x + bv.x,
                                          (sxv.y - mu) * inv * wv.y + bv.y);
            if (b == bsel + 2) ((float2*)(sd_out + le))[t] = x2;  // sd (host-only)
            const float2 sdv = ((const float2*)(state + 3 * LNUM * EDIM + le))[t];
            const float2 mkf = ((const float2*)(mixkf + le))[t];
            const float2 mrf = ((const float2*)(mixrf + le))[t];
            ((float2*)smem)[t] = make_float2(x2.x + mkf.x * sdv.x, x2.y + mkf.y * sdv.y);
            ((float2*)(smem + 1024))[t] =
                make_float2(x2.x + mrf.x * sdv.x, x2.y + mrf.y * sdv.y);
            lbar();
            const float d1 = dot1024_pref(pC10, pC11, pC12, pC13, smem, lane);
            const float d2 = dot1024_pref(pC20, pC21, pC22, pC23, smem, lane);
            const float d3 = dot512_pref(rC0, rC1, smem + 1024 + (rh << 9), lane);
            if (lane == 0) { red[w] = d1; red[8 + w] = d2; red[16 + w] = d3; }
            lbar();
            if (w == 0) {  // wave-0 tail: kf stores + local gates
                if (lane < 8) {
                    const float r1 = fmaxf(red[lane], 0.0f);
                    const float r2 = fmaxf(red[8 + lane], 0.0f);
                    cstore1(kfbuf + (b << 3) + lane, r1 * r1);
                    cstore1(kfbuf + 2048 + (b << 3) + lane, r2 * r2);
                } else if (lane < 12) {
                    const int j = lane - 8;
                    red[32 + j] =
                        1.0f / (1.0f + expf(red[16 + 2 * j] + red[17 + 2 * j]));
                }
            }
        }
        FENCE();
        {   // window C->D: both vfw chunk-units = 8 loads
            const float4* q1 = (const float4*)(vfl + ((size_t)drow << 12) + (dch << 10));
            pD0 = q1[lane]; pD1 = q1[lane + 64]; pD2 = q1[lane + 128]; pD3 = q1[lane + 192];
            const float4* q2 =
                (const float4*)(vfl + ((size_t)(drow + 2) << 12) + (dch << 10));
            pD4 = q2[lane]; pD5 = q2[lane + 64]; pD6 = q2[lane + 128]; pD7 = q2[lane + 192];
        }
        gbar<8>(grp, flags, bi, w);

        // ========== Phase D: vfw matvec + gated residual (fully local tail) ==========
        {
            const double* kfd = (const double*)kfbuf;
#pragma unroll
            for (int j = 0; j < 4; ++j)
                ((double*)smem)[t + j * 512] = __hip_atomic_load(
                    kfd + t + j * 512, __ATOMIC_RELAXED, __HIP_MEMORY_SCOPE_AGENT);
            lbar();
            const float pd0 = dot1024_pref(pD0, pD1, pD2, pD3, smem + (dch << 10), lane);
            const float pd1 = dot1024_pref(pD4, pD5, pD6, pD7, smem + (dch << 10), lane);
            if (lane == 0) { red[w] = pd0; red[8 + w] = pd1; }
            lbar();
            if (w == 0 && lane < 4) {  // x' = sx + ffn*gate — sx, gate in LDS
                const float ffn = red[4 * lane] + red[4 * lane + 1] +
                                  red[4 * lane + 2] + red[4 * lane + 3];
                const float val = red[28 + lane] + ffn * red[32 + lane];
                if (l == LNUM - 1) out[(b << 2) + lane] = val;  // final output
                else cstore1(xnext + (b << 2) + lane, val);
            }
        }
        if (l < LNUM - 1) {
            FENCE();
            {   // window D->A': next layer's phase-A weights = 6 loads
                const float* keyn = key + (size_t)(l + 1) * 3 * EDIM * EDIM;
                const float4* qA = (const float4*)(keyn + ((size_t)gw << 10));
                pA0 = qA[lane]; pA1 = qA[lane + 64]; pA2 = qA[lane + 128]; pA3 = qA[lane + 192];
                const float4* qR =
                    (const float4*)(keyn + ((size_t)(2048 + rrow) << 10) + (rh << 9));
                rA0 = qR[lane]; rA1 = qR[lane + 64];
            }
            gbar<6>(grp, flags, bi, w);
        }
    }
}

extern "C" void kernel_launch(void* const* d_in, const int* in_sizes, int n_in,
                              void* d_out, int out_size, void* d_ws, size_t ws_size,
                              hipStream_t stream) {
    const float* x_in = (const float*)d_in[0];
    const float* state = (const float*)d_in[1];
    const float* ln1w = (const float*)d_in[2];
    const float* ln1b = (const float*)d_in[3];
    const float* ln2w = (const float*)d_in[4];
    const float* ln2b = (const float*)d_in[5];
    const float* td = (const float*)d_in[6];
    const float* tf = (const float*)d_in[7];
    const float* key = (const float*)d_in[8];
    const float* ow = (const float*)d_in[9];
    const float* mixk = (const float*)d_in[10];
    const float* mixv = (const float*)d_in[11];
    const float* mixr = (const float*)d_in[12];
    const float* mixkf = (const float*)d_in[13];
    const float* mixrf = (const float*)d_in[14];
    const float* kffn = (const float*)d_in[15];
    const float* rffn = (const float*)d_in[16];
    const float* vffn = (const float*)d_in[17];

    float* out = (float*)d_out;
    float* ws = (float*)d_ws;

    // Vector region: 9216 floats = 36 KB. Barrier state at 48 KB:
    // 8 arrival lines, then 256 per-block release flag lines (64 B each).
    unsigned* bar = (unsigned*)((char*)d_ws + 48 * 1024);
    unsigned* grp = bar;           // grp[g<<4], g=0..7
    unsigned* flags = bar + 1024;  // flags[b<<4], b=0..255 (16 KB)

    hipMemsetAsync(bar, 0, 24 * 1024, stream);  // deterministic per replay
    rwkv_persistent<<<NB, NT, 0, stream>>>(x_in, state, ln1w, ln1b, ln2w, ln2b, td, tf,
                                           key, ow, mixk, mixv, mixr, mixkf, mixrf,
                                           kffn, rffn, vffn, out, ws, grp, flags);
}